// Round 4
// baseline (2524.207 us; speedup 1.0000x reference)
//
#include <hip/hip_runtime.h>
#include <math.h>

#define NPTS 4096
#define DIM 64
#define LOGW2 (-12.0f)               // -log2(4096)  (log-domain is base-2)
#define NEGINF (-__builtin_inff())

typedef __bf16 bf16x8 __attribute__((ext_vector_type(8)));
typedef float f32x4 __attribute__((ext_vector_type(4)));

static __device__ __forceinline__ f32x4 mfma16(bf16x8 a, bf16x8 b, f32x4 c) {
  return __builtin_amdgcn_mfma_f32_16x16x32_bf16(a, b, c, 0, 0, 0);
}
// raw hardware base-2 transcendentals (v_exp_f32 / v_log_f32)
static __device__ __forceinline__ float exp2v(float x) {
  return __builtin_amdgcn_exp2f(x);
}
static __device__ __forceinline__ float log2v(float x) {
  return __builtin_amdgcn_logf(x);
}

// ---------------------------------------------------------------------------
// Normalize rows to unit L2 norm and split into bf16 hi/lo pairs
// (v = hi + lo with |lo| <= 2^-9 |v| -> split-bf16 GEMM gives ~fp32 accuracy).
// One wave per row; grid 2048 x 256 covers 8192 rows (x then y).
// ---------------------------------------------------------------------------
__global__ __launch_bounds__(256) void norm_split_kernel(
    const float* __restrict__ x, const float* __restrict__ y,
    __bf16* __restrict__ xh, __bf16* __restrict__ xl,
    __bf16* __restrict__ yh, __bf16* __restrict__ yl) {
  int row  = blockIdx.x * 4 + (threadIdx.x >> 6);
  int lane = threadIdx.x & 63;
  const float* src; __bf16 *dh, *dl;
  if (row < NPTS) {
    src = x + (size_t)row * DIM; dh = xh + (size_t)row * DIM; dl = xl + (size_t)row * DIM;
  } else {
    int r = row - NPTS;
    src = y + (size_t)r * DIM; dh = yh + (size_t)r * DIM; dl = yl + (size_t)r * DIM;
  }
  float v = src[lane];
  float s = v * v;
  #pragma unroll
  for (int o = 32; o; o >>= 1) s += __shfl_xor(s, o, 64);
  v *= 1.0f / sqrtf(s);
  __bf16 h = (__bf16)v;
  __bf16 l = (__bf16)(v - (float)h);
  dh[lane] = h;
  dl[lane] = l;
}

// ---------------------------------------------------------------------------
// FUSED sweep (v2): recompute cost tiles via split-bf16 MFMA, feed fp32
// accumulators straight into an online row-logsumexp in the BASE-2 log
// domain (inv_eps2 = log2(e)/eps folded in; every exp is a bare v_exp_f32).
//
// Round-2 lesson: 256 blocks x 4 waves = 1 wave/SIMD -> 45% stall, 63 us.
// Now: grid = 4 mats x 256 row-blocks (16 rows each) = 1024 blocks of 256
// threads, __launch_bounds__(256,4) -> 4 blocks/CU = 4 waves/SIMD.
// Wave w owns cols [w*1024, (w+1)*1024) = 64 col-tiles, processed in PAIRS:
// the D-frag's 4 q-values are 4 different rows, but the same (quad,q) slot
// of consecutive col-tiles is the SAME row -> 2-element blocked LSE update
// (1 running-max merge + 1 rescale per 2 elements):
//   bm = max(tv0,tv1); mn = max(m,bm);
//   s  = s*exp2(m-mn) + exp2(tv0-mn) + exp2(tv1-mn); m = mn;
// m = -inf start: exp2(-inf-mn) = 0, first chunk exact.
// 6 MFMA per 16x16 tile (hi.hi k0,k1 + lo.hi k0,k1 + hi.lo k0,k1).
// A-frag: lane L holds A[m=L&15][k=(L>>4)*8+j]; C/D: col=L&15, row=(L>>4)*4+q.
// tv = h2_j - cost/eps*log2e = fma(min(dot,1), inv_eps2, h2_j - inv_eps2).
// Final: ft = -eps*ln(sum) = -(eps*ln2)*(m + log2(s)).
// ---------------------------------------------------------------------------
__global__ __launch_bounds__(256, 4) void fused_pass_kernel(
    const __bf16* __restrict__ xh, const __bf16* __restrict__ xl,
    const __bf16* __restrict__ yh, const __bf16* __restrict__ yl,
    const float* __restrict__ potOld, float* __restrict__ potNew,
    float inv_eps2, float epsl2, int use_pot, int avg) {
  __shared__ float hlds[NPTS];       // 16 KB: h2[j] = -12 + pot[j]*inv_eps2
  __shared__ float mred[4][16];
  __shared__ float sred[4][16];

  int mat = blockIdx.x >> 8;
  int rb  = blockIdx.x & 255;
  const __bf16 *Ah, *Al, *Bh, *Bl;
  if (mat == 0)      { Ah = xh; Al = xl; Bh = yh; Bl = yl; }
  else if (mat == 1) { Ah = yh; Al = yl; Bh = xh; Bl = xl; }
  else if (mat == 2) { Ah = xh; Al = xl; Bh = xh; Bl = xl; }
  else               { Ah = yh; Al = yl; Bh = yh; Bl = yl; }
  int ridx = (mat == 0) ? 1 : ((mat == 1) ? 0 : mat);
  const float* pot = potOld + (size_t)ridx * NPTS;

  // stage h2[] into LDS (float4 vectorized)
  for (int j4 = threadIdx.x; j4 < NPTS / 4; j4 += 256) {
    float4 p;
    if (use_pot) {
      float4 q = *(const float4*)(pot + j4 * 4);
      p.x = fmaf(q.x, inv_eps2, LOGW2); p.y = fmaf(q.y, inv_eps2, LOGW2);
      p.z = fmaf(q.z, inv_eps2, LOGW2); p.w = fmaf(q.w, inv_eps2, LOGW2);
    } else {
      p.x = p.y = p.z = p.w = LOGW2;
    }
    *(float4*)(hlds + j4 * 4) = p;
  }
  __syncthreads();

  int wave = threadIdx.x >> 6, L = threadIdx.x & 63;
  int mrow = L & 15, quad = L >> 4;
  int i0 = rb * 16;

  // A fragments for the block's single 16-row set (16 VGPRs)
  size_t ab = (size_t)(i0 + mrow) * DIM + quad * 8;
  bf16x8 Afh0 = *(const bf16x8*)(Ah + ab);
  bf16x8 Afh1 = *(const bf16x8*)(Ah + ab + 32);
  bf16x8 Afl0 = *(const bf16x8*)(Al + ab);
  bf16x8 Afl1 = *(const bf16x8*)(Al + ab + 32);

  // online-LSE state: 4 (m,s) pairs (rows quad*4+q), base-2 log domain
  float sm0 = NEGINF, sm1 = NEGINF, sm2 = NEGINF, sm3 = NEGINF;
  float ss0 = 0.0f, ss1 = 0.0f, ss2 = 0.0f, ss3 = 0.0f;

  int jw = wave * 1024;

  #pragma unroll 2
  for (int tp = 0; tp < 32; ++tp) {
    // col-tile pair t0 = 2*tp, t1 = 2*tp+1 (same rows -> shared LSE chunk)
    size_t b0 = (size_t)(jw + tp * 32 + mrow) * DIM + quad * 8;
    size_t b1 = b0 + 16 * DIM;
    bf16x8 b0h0 = *(const bf16x8*)(Bh + b0);
    bf16x8 b0h1 = *(const bf16x8*)(Bh + b0 + 32);
    bf16x8 b0l0 = *(const bf16x8*)(Bl + b0);
    bf16x8 b0l1 = *(const bf16x8*)(Bl + b0 + 32);
    bf16x8 b1h0 = *(const bf16x8*)(Bh + b1);
    bf16x8 b1h1 = *(const bf16x8*)(Bh + b1 + 32);
    bf16x8 b1l0 = *(const bf16x8*)(Bl + b1);
    bf16x8 b1l1 = *(const bf16x8*)(Bl + b1 + 32);
    float hp0 = hlds[jw + tp * 32 + mrow] - inv_eps2;
    float hp1 = hlds[jw + tp * 32 + 16 + mrow] - inv_eps2;

    f32x4 acc0 = {0.0f, 0.0f, 0.0f, 0.0f};
    acc0 = mfma16(Afh0, b0h0, acc0);
    acc0 = mfma16(Afh1, b0h1, acc0);
    acc0 = mfma16(Afl0, b0h0, acc0);
    acc0 = mfma16(Afl1, b0h1, acc0);
    acc0 = mfma16(Afh0, b0l0, acc0);
    acc0 = mfma16(Afh1, b0l1, acc0);
    f32x4 acc1 = {0.0f, 0.0f, 0.0f, 0.0f};
    acc1 = mfma16(Afh0, b1h0, acc1);
    acc1 = mfma16(Afh1, b1h1, acc1);
    acc1 = mfma16(Afl0, b1h0, acc1);
    acc1 = mfma16(Afl1, b1h1, acc1);
    acc1 = mfma16(Afh0, b1l0, acc1);
    acc1 = mfma16(Afh1, b1l1, acc1);

    // 2-element blocked LSE update per row accumulator
    {
      float tv0 = fmaf(fminf(acc0[0], 1.0f), inv_eps2, hp0);
      float tv1 = fmaf(fminf(acc1[0], 1.0f), inv_eps2, hp1);
      float mn = fmaxf(sm0, fmaxf(tv0, tv1));
      ss0 = fmaf(ss0, exp2v(sm0 - mn), exp2v(tv0 - mn) + exp2v(tv1 - mn));
      sm0 = mn;
    }
    {
      float tv0 = fmaf(fminf(acc0[1], 1.0f), inv_eps2, hp0);
      float tv1 = fmaf(fminf(acc1[1], 1.0f), inv_eps2, hp1);
      float mn = fmaxf(sm1, fmaxf(tv0, tv1));
      ss1 = fmaf(ss1, exp2v(sm1 - mn), exp2v(tv0 - mn) + exp2v(tv1 - mn));
      sm1 = mn;
    }
    {
      float tv0 = fmaf(fminf(acc0[2], 1.0f), inv_eps2, hp0);
      float tv1 = fmaf(fminf(acc1[2], 1.0f), inv_eps2, hp1);
      float mn = fmaxf(sm2, fmaxf(tv0, tv1));
      ss2 = fmaf(ss2, exp2v(sm2 - mn), exp2v(tv0 - mn) + exp2v(tv1 - mn));
      sm2 = mn;
    }
    {
      float tv0 = fmaf(fminf(acc0[3], 1.0f), inv_eps2, hp0);
      float tv1 = fmaf(fminf(acc1[3], 1.0f), inv_eps2, hp1);
      float mn = fmaxf(sm3, fmaxf(tv0, tv1));
      ss3 = fmaf(ss3, exp2v(sm3 - mn), exp2v(tv0 - mn) + exp2v(tv1 - mn));
      sm3 = mn;
    }
  }

  // merge (m,s) across the 16 col-lanes of each quad group
  float sm[4] = {sm0, sm1, sm2, sm3};
  float ss[4] = {ss0, ss1, ss2, ss3};
  #pragma unroll
  for (int o = 1; o < 16; o <<= 1) {
    #pragma unroll
    for (int i = 0; i < 4; ++i) {
      float m2 = __shfl_xor(sm[i], o, 64);
      float s2 = __shfl_xor(ss[i], o, 64);
      float mn = fmaxf(sm[i], m2);
      ss[i] = ss[i] * exp2v(sm[i] - mn) + s2 * exp2v(m2 - mn);
      sm[i] = mn;
    }
  }

  // per-wave partials -> LDS (row = quad*4 + q)
  if (mrow == 0) {
    #pragma unroll
    for (int q = 0; q < 4; ++q) {
      mred[wave][quad * 4 + q] = sm[q];
      sred[wave][quad * 4 + q] = ss[q];
    }
  }
  __syncthreads();

  // merge 4 waves (disjoint col ranges), finalize, write potential
  if (threadIdx.x < 16) {
    int row = threadIdx.x;
    float m = mred[0][row], s = sred[0][row];
    #pragma unroll
    for (int w = 1; w < 4; ++w) {
      float m2 = mred[w][row], s2 = sred[w][row];
      float mn = fmaxf(m, m2);
      s = s * exp2v(m - mn) + s2 * exp2v(m2 - mn);
      m = mn;
    }
    float ft = -epsl2 * (m + log2v(s));
    float v = avg ? 0.5f * (potOld[(size_t)mat * NPTS + i0 + row] + ft) : ft;
    potNew[(size_t)mat * NPTS + i0 + row] = v;
  }
}

// ---------------------------------------------------------------------------
// out = mean(f_ba - f_aa) + mean(g_ab - g_bb), potentials at pot[0..3][NPTS]
// ---------------------------------------------------------------------------
__global__ __launch_bounds__(256) void final_kernel(
    const float* __restrict__ pot, float* __restrict__ out) {
  __shared__ float red[256];
  float s = 0.0f;
  for (int j = threadIdx.x; j < NPTS; j += 256)
    s += (pot[j] - pot[2 * NPTS + j]) + (pot[NPTS + j] - pot[3 * NPTS + j]);
  red[threadIdx.x] = s;
  __syncthreads();
  #pragma unroll
  for (int o = 128; o; o >>= 1) {
    if (threadIdx.x < o) red[threadIdx.x] += red[threadIdx.x + o];
    __syncthreads();
  }
  if (threadIdx.x == 0) out[0] = red[0] / (float)NPTS;
}

extern "C" void kernel_launch(void* const* d_in, const int* in_sizes, int n_in,
                              void* d_out, int out_size, void* d_ws, size_t ws_size,
                              hipStream_t stream) {
  const float* x = (const float*)d_in[0];
  const float* y = (const float*)d_in[1];
  char* ws = (char*)d_ws;

  // workspace layout (no cost matrix: ~2.3 MB total)
  __bf16* xh = (__bf16*)ws;
  __bf16* xl = xh + (size_t)NPTS * DIM;
  __bf16* yh = xl + (size_t)NPTS * DIM;
  __bf16* yl = yh + (size_t)NPTS * DIM;
  float* potA = (float*)(yl + (size_t)NPTS * DIM);    // 4 * NPTS
  float* potB = potA + 4 * (size_t)NPTS;
  size_t needed = (size_t)((char*)(potB + 4 * (size_t)NPTS) - ws);
  if (ws_size < needed) return;

  norm_split_kernel<<<2048, 256, 0, stream>>>(x, y, xh, xl, yh, yl);

  // geomloss epsilon schedule (p=2, blur=0.05, scaling=0.8, diameter=2)
  double lst[32];
  int c = 0;
  lst[c++] = 4.0;
  double start = 2.0 * log(2.0), stop = 2.0 * log(0.05), step = 2.0 * log(0.8);
  for (int k = 0;; ++k) {
    double v = start + (double)k * step;
    if (v <= stop) break;
    lst[c++] = exp(v);
  }
  lst[c++] = 0.05 * 0.05;   // c == 19

  const double LOG2E = 1.4426950408889634074;
  const double LN2   = 0.6931471805599453094;

  // sweeps: p=0 init (no pot, assign); p=1..c loop (avg); p=c+1 final (assign)
  for (int p = 0; p < c + 2; ++p) {
    double e = (p == 0) ? lst[0] : ((p <= c) ? lst[p - 1] : lst[c - 1]);
    float inv_eps2 = (float)(LOG2E / e);   // log2(e)/eps
    float epsl2    = (float)(e * LN2);     // eps*ln(2)
    int use_pot = (p > 0) ? 1 : 0;
    int avg = (p >= 1 && p <= c) ? 1 : 0;
    const float* po = (p & 1) ? potB : potA;
    float* pn       = (p & 1) ? potA : potB;
    fused_pass_kernel<<<1024, 256, 0, stream>>>(xh, xl, yh, yl, po, pn,
                                                inv_eps2, epsl2, use_pot, avg);
  }
  // c+2 = 21 sweeps; last sweep (p=20, even) wrote potB
  final_kernel<<<1, 256, 0, stream>>>(potB, (float*)d_out);
}

// Round 5
// 786.986 us; speedup vs baseline: 3.2074x; 3.2074x over previous
//
#include <hip/hip_runtime.h>
#include <math.h>

#define NPTS 4096
#define DIM 64
#define LOGW2 (-12.0f)               // -log2(4096)  (log-domain is base-2)
#define NEGINF (-__builtin_inff())

typedef __bf16 bf16x8 __attribute__((ext_vector_type(8)));
typedef float f32x4 __attribute__((ext_vector_type(4)));

static __device__ __forceinline__ f32x4 mfma16(bf16x8 a, bf16x8 b, f32x4 c) {
  return __builtin_amdgcn_mfma_f32_16x16x32_bf16(a, b, c, 0, 0, 0);
}
// raw hardware base-2 transcendentals (v_exp_f32 / v_log_f32)
static __device__ __forceinline__ float exp2v(float x) {
  return __builtin_amdgcn_exp2f(x);
}
static __device__ __forceinline__ float log2v(float x) {
  return __builtin_amdgcn_logf(x);
}

// ---------------------------------------------------------------------------
// Normalize rows to unit L2 norm, split into bf16 hi/lo, and REPACK into the
// MFMA fragment-tile layout so the GEMM kernel's loads are lane-contiguous:
//   tile t (16 rows), chunk c in {0,1}, lane L = quad*16 + mrow:
//     offset(t,c,L,j) = t*1024 + c*512 + L*8 + j    (bf16 elements, j<8)
//     holds element [row = t*16 + mrow][k = c*32 + quad*8 + j].
// A-frag and B-frag (B^T GEMM) use the SAME layout -> one copy serves both.
// grid 256 x 256 thr; block = 32 rows (2 tiles) of x or y, via LDS transpose.
// ---------------------------------------------------------------------------
__global__ __launch_bounds__(256) void norm_repack_kernel(
    const float* __restrict__ x, const float* __restrict__ y,
    __bf16* __restrict__ xhf, __bf16* __restrict__ xlf,
    __bf16* __restrict__ yhf, __bf16* __restrict__ ylf) {
  __shared__ float tf[32][72];       // +8 pad: 16B-aligned rows, bank-spread
  int r0 = blockIdx.x * 32;
  const float* src;
  __bf16 *dh, *dl;
  int rbase;
  if (r0 < NPTS) { src = x; dh = xhf; dl = xlf; rbase = r0; }
  else           { src = y; dh = yhf; dl = ylf; rbase = r0 - NPTS; }

  int wave = threadIdx.x >> 6, lane = threadIdx.x & 63;
  #pragma unroll
  for (int i = 0; i < 8; ++i) {
    int wrow = wave * 8 + i;
    float v = src[(size_t)(rbase + wrow) * DIM + lane];
    float s = v * v;
    #pragma unroll
    for (int o = 32; o; o >>= 1) s += __shfl_xor(s, o, 64);
    tf[wrow][lane] = v * (1.0f / sqrtf(s));
  }
  __syncthreads();

  int tt   = threadIdx.x >> 7;        // tile within block (0/1)
  int idx  = threadIdx.x & 127;
  int c    = idx >> 6, L = idx & 63;
  int quad = L >> 4, mrow = L & 15;
  const float* rp = &tf[tt * 16 + mrow][c * 32 + quad * 8];
  bf16x8 hv, lv;
  #pragma unroll
  for (int j = 0; j < 8; ++j) {
    float v = rp[j];
    __bf16 h = (__bf16)v;
    hv[j] = h;
    lv[j] = (__bf16)(v - (float)h);
  }
  size_t ob = (size_t)(rbase / 16 + tt) * 1024 + c * 512 + L * 8;
  *(bf16x8*)(dh + ob) = hv;           // fully coalesced 16B/lane writes
  *(bf16x8*)(dl + ob) = lv;
}

// ---------------------------------------------------------------------------
// FUSED sweep (v3): recompute cost tiles via split-bf16 MFMA from the
// fragment-tile layout, feed fp32 accumulators straight into an online
// row-logsumexp in the base-2 log domain.
//
// Round-4 lesson: strided per-lane fragment gathers (16 half-lines per load
// instr) saturate the L1/L2 request path -- extra occupancy hid nothing.
// Now every load is lane-contiguous (8 full 128B lines per instr) with a
// loop-invariant voffset, and 2 row-sets amortize each B-load over 24 MFMA.
//
// Grid: 4 mats x 128 row-blocks = 512 blocks x 512 thr (8 waves) =
// 2 blocks/CU = 4 waves/SIMD. Block = 32 rows x 4096 cols; wave owns
// 512 cols = 32 col-tiles, processed in pairs (2-element blocked LSE:
// same (quad,q) slot of consecutive tiles is the same row).
// 6 MFMA per 16x16 tile (hi.hi c0,c1 + lo.hi c0,c1 + hi.lo c0,c1).
// C/D frag: col = L&15 (= h index), row = (L>>4)*4 + q within the row-set.
// tv = h2_j - cost*inv_eps2 = fma(min(dot,1), inv_eps2, h2_j - inv_eps2).
// Merge: shfl over 16 col-lanes, then LDS merge across 8 waves.
// Final: ft = -eps*ln(sum) = -(eps*ln2)*(m + log2(s)).
// ---------------------------------------------------------------------------
__global__ __launch_bounds__(512, 4) void fused_pass_kernel(
    const __bf16* __restrict__ xhf, const __bf16* __restrict__ xlf,
    const __bf16* __restrict__ yhf, const __bf16* __restrict__ ylf,
    const float* __restrict__ potOld, float* __restrict__ potNew,
    float inv_eps2, float epsl2, int use_pot, int avg) {
  __shared__ float hlds[NPTS];       // 16 KB: h2[j] = -12 + pot[j]*inv_eps2
  __shared__ float mred[8][32];
  __shared__ float sred[8][32];

  int mat = blockIdx.x >> 7;
  int rb  = blockIdx.x & 127;
  const __bf16 *Ah, *Al, *Bh, *Bl;
  if (mat == 0)      { Ah = xhf; Al = xlf; Bh = yhf; Bl = ylf; }
  else if (mat == 1) { Ah = yhf; Al = ylf; Bh = xhf; Bl = xlf; }
  else if (mat == 2) { Ah = xhf; Al = xlf; Bh = xhf; Bl = xlf; }
  else               { Ah = yhf; Al = ylf; Bh = yhf; Bl = ylf; }
  int ridx = (mat == 0) ? 1 : ((mat == 1) ? 0 : mat);
  const float* pot = potOld + (size_t)ridx * NPTS;

  // stage h2[] into LDS: 512 thr x 8 floats
  {
    int j8 = threadIdx.x * 8;
    float4 p0, p1;
    if (use_pot) {
      float4 q0 = *(const float4*)(pot + j8);
      float4 q1 = *(const float4*)(pot + j8 + 4);
      p0.x = fmaf(q0.x, inv_eps2, LOGW2); p0.y = fmaf(q0.y, inv_eps2, LOGW2);
      p0.z = fmaf(q0.z, inv_eps2, LOGW2); p0.w = fmaf(q0.w, inv_eps2, LOGW2);
      p1.x = fmaf(q1.x, inv_eps2, LOGW2); p1.y = fmaf(q1.y, inv_eps2, LOGW2);
      p1.z = fmaf(q1.z, inv_eps2, LOGW2); p1.w = fmaf(q1.w, inv_eps2, LOGW2);
    } else {
      p0.x = p0.y = p0.z = p0.w = LOGW2;
      p1 = p0;
    }
    *(float4*)(hlds + j8) = p0;
    *(float4*)(hlds + j8 + 4) = p1;
  }
  __syncthreads();

  int wave = threadIdx.x >> 6, L = threadIdx.x & 63;
  int mrow = L & 15, quad = L >> 4;
  int lofs = L * 8;
  int i0 = rb * 32;

  // A fragments: 2 row-sets (tiles rb*2, rb*2+1), 32 VGPR
  bf16x8 Ah0[2], Ah1[2], Al0[2], Al1[2];
  #pragma unroll
  for (int rs = 0; rs < 2; ++rs) {
    size_t ab = (size_t)(rb * 2 + rs) * 1024 + lofs;
    Ah0[rs] = *(const bf16x8*)(Ah + ab);
    Ah1[rs] = *(const bf16x8*)(Ah + ab + 512);
    Al0[rs] = *(const bf16x8*)(Al + ab);
    Al1[rs] = *(const bf16x8*)(Al + ab + 512);
  }

  // online-LSE state: 8 (m,s) pairs (2 sets x 4 sub-rows), base-2 log domain
  float sm[8], ss[8];
  #pragma unroll
  for (int i = 0; i < 8; ++i) { sm[i] = NEGINF; ss[i] = 0.0f; }

  size_t jt0 = (size_t)(wave * 32) * 1024 + lofs;   // wave's first tile
  int hb0 = wave * 512;

  #pragma unroll 1
  for (int tp = 0; tp < 16; ++tp) {
    // col-tile pair 2*tp, 2*tp+1 (same rows -> shared 2-elem LSE chunk)
    size_t o0 = jt0 + (size_t)tp * 2048;
    bf16x8 b0h0 = *(const bf16x8*)(Bh + o0);
    bf16x8 b0h1 = *(const bf16x8*)(Bh + o0 + 512);
    bf16x8 b0l0 = *(const bf16x8*)(Bl + o0);
    bf16x8 b0l1 = *(const bf16x8*)(Bl + o0 + 512);
    bf16x8 b1h0 = *(const bf16x8*)(Bh + o0 + 1024);
    bf16x8 b1h1 = *(const bf16x8*)(Bh + o0 + 1536);
    bf16x8 b1l0 = *(const bf16x8*)(Bl + o0 + 1024);
    bf16x8 b1l1 = *(const bf16x8*)(Bl + o0 + 1536);
    float hp0 = hlds[hb0 + tp * 32 + mrow] - inv_eps2;
    float hp1 = hlds[hb0 + tp * 32 + 16 + mrow] - inv_eps2;

    #pragma unroll
    for (int rs = 0; rs < 2; ++rs) {
      f32x4 acc0 = {0.0f, 0.0f, 0.0f, 0.0f};
      acc0 = mfma16(Ah0[rs], b0h0, acc0);
      acc0 = mfma16(Ah1[rs], b0h1, acc0);
      acc0 = mfma16(Al0[rs], b0h0, acc0);
      acc0 = mfma16(Al1[rs], b0h1, acc0);
      acc0 = mfma16(Ah0[rs], b0l0, acc0);
      acc0 = mfma16(Ah1[rs], b0l1, acc0);
      f32x4 acc1 = {0.0f, 0.0f, 0.0f, 0.0f};
      acc1 = mfma16(Ah0[rs], b1h0, acc1);
      acc1 = mfma16(Ah1[rs], b1h1, acc1);
      acc1 = mfma16(Al0[rs], b1h0, acc1);
      acc1 = mfma16(Al1[rs], b1h1, acc1);
      acc1 = mfma16(Ah0[rs], b1l0, acc1);
      acc1 = mfma16(Ah1[rs], b1l1, acc1);
      #pragma unroll
      for (int q = 0; q < 4; ++q) {
        int id = rs * 4 + q;
        float tv0 = fmaf(fminf(acc0[q], 1.0f), inv_eps2, hp0);
        float tv1 = fmaf(fminf(acc1[q], 1.0f), inv_eps2, hp1);
        float mn = fmaxf(sm[id], fmaxf(tv0, tv1));
        ss[id] = fmaf(ss[id], exp2v(sm[id] - mn),
                      exp2v(tv0 - mn) + exp2v(tv1 - mn));
        sm[id] = mn;
      }
    }
  }

  // merge (m,s) across the 16 col-lanes of each quad group
  #pragma unroll
  for (int o = 1; o < 16; o <<= 1) {
    #pragma unroll
    for (int i = 0; i < 8; ++i) {
      float m2 = __shfl_xor(sm[i], o, 64);
      float s2 = __shfl_xor(ss[i], o, 64);
      float mn = fmaxf(sm[i], m2);
      ss[i] = ss[i] * exp2v(sm[i] - mn) + s2 * exp2v(m2 - mn);
      sm[i] = mn;
    }
  }

  // per-wave partials -> LDS (row within block = rs*16 + quad*4 + q)
  if (mrow == 0) {
    #pragma unroll
    for (int rs = 0; rs < 2; ++rs)
      #pragma unroll
      for (int q = 0; q < 4; ++q) {
        int row = rs * 16 + quad * 4 + q;
        mred[wave][row] = sm[rs * 4 + q];
        sred[wave][row] = ss[rs * 4 + q];
      }
  }
  __syncthreads();

  // merge 8 waves (disjoint col ranges), finalize, write potential
  if (threadIdx.x < 32) {
    int row = threadIdx.x;
    float m = mred[0][row], s = sred[0][row];
    #pragma unroll
    for (int w = 1; w < 8; ++w) {
      float m2 = mred[w][row], s2 = sred[w][row];
      float mn = fmaxf(m, m2);
      s = s * exp2v(m - mn) + s2 * exp2v(m2 - mn);
      m = mn;
    }
    float ft = -epsl2 * (m + log2v(s));
    float v = avg ? 0.5f * (potOld[(size_t)mat * NPTS + i0 + row] + ft) : ft;
    potNew[(size_t)mat * NPTS + i0 + row] = v;
  }
}

// ---------------------------------------------------------------------------
// out = mean(f_ba - f_aa) + mean(g_ab - g_bb), potentials at pot[0..3][NPTS]
// ---------------------------------------------------------------------------
__global__ __launch_bounds__(256) void final_kernel(
    const float* __restrict__ pot, float* __restrict__ out) {
  __shared__ float red[256];
  float s = 0.0f;
  for (int j = threadIdx.x; j < NPTS; j += 256)
    s += (pot[j] - pot[2 * NPTS + j]) + (pot[NPTS + j] - pot[3 * NPTS + j]);
  red[threadIdx.x] = s;
  __syncthreads();
  #pragma unroll
  for (int o = 128; o; o >>= 1) {
    if (threadIdx.x < o) red[threadIdx.x] += red[threadIdx.x + o];
    __syncthreads();
  }
  if (threadIdx.x == 0) out[0] = red[0] / (float)NPTS;
}

extern "C" void kernel_launch(void* const* d_in, const int* in_sizes, int n_in,
                              void* d_out, int out_size, void* d_ws, size_t ws_size,
                              hipStream_t stream) {
  const float* x = (const float*)d_in[0];
  const float* y = (const float*)d_in[1];
  char* ws = (char*)d_ws;

  // workspace layout (~2.2 MB): fragment-packed hi/lo matrices + potentials
  __bf16* xhf = (__bf16*)ws;
  __bf16* xlf = xhf + (size_t)NPTS * DIM;
  __bf16* yhf = xlf + (size_t)NPTS * DIM;
  __bf16* ylf = yhf + (size_t)NPTS * DIM;
  float* potA = (float*)(ylf + (size_t)NPTS * DIM);   // 4 * NPTS
  float* potB = potA + 4 * (size_t)NPTS;
  size_t needed = (size_t)((char*)(potB + 4 * (size_t)NPTS) - ws);
  if (ws_size < needed) return;

  norm_repack_kernel<<<256, 256, 0, stream>>>(x, y, xhf, xlf, yhf, ylf);

  // geomloss epsilon schedule (p=2, blur=0.05, scaling=0.8, diameter=2)
  double lst[32];
  int c = 0;
  lst[c++] = 4.0;
  double start = 2.0 * log(2.0), stop = 2.0 * log(0.05), step = 2.0 * log(0.8);
  for (int k = 0;; ++k) {
    double v = start + (double)k * step;
    if (v <= stop) break;
    lst[c++] = exp(v);
  }
  lst[c++] = 0.05 * 0.05;   // c == 19

  const double LOG2E = 1.4426950408889634074;
  const double LN2   = 0.6931471805599453094;

  // sweeps: p=0 init (no pot, assign); p=1..c loop (avg); p=c+1 final (assign)
  for (int p = 0; p < c + 2; ++p) {
    double e = (p == 0) ? lst[0] : ((p <= c) ? lst[p - 1] : lst[c - 1]);
    float inv_eps2 = (float)(LOG2E / e);   // log2(e)/eps
    float epsl2    = (float)(e * LN2);     // eps*ln(2)
    int use_pot = (p > 0) ? 1 : 0;
    int avg = (p >= 1 && p <= c) ? 1 : 0;
    const float* po = (p & 1) ? potB : potA;
    float* pn       = (p & 1) ? potA : potB;
    fused_pass_kernel<<<512, 512, 0, stream>>>(xhf, xlf, yhf, ylf, po, pn,
                                               inv_eps2, epsl2, use_pot, avg);
  }
  // c+2 = 21 sweeps; last sweep (p=20, even) wrote potB
  final_kernel<<<1, 256, 0, stream>>>(potB, (float*)d_out);
}

// Round 6
// 772.002 us; speedup vs baseline: 3.2697x; 1.0194x over previous
//
#include <hip/hip_runtime.h>
#include <math.h>

#define NPTS 4096
#define DIM 64
#define LOGW2 (-12.0f)               // -log2(4096)  (log-domain is base-2)
#define NEGINF (-__builtin_inff())

typedef __bf16 bf16x8 __attribute__((ext_vector_type(8)));
typedef float f32x4 __attribute__((ext_vector_type(4)));

static __device__ __forceinline__ f32x4 mfma16(bf16x8 a, bf16x8 b, f32x4 c) {
  return __builtin_amdgcn_mfma_f32_16x16x32_bf16(a, b, c, 0, 0, 0);
}
// raw hardware base-2 transcendentals (v_exp_f32 / v_log_f32)
static __device__ __forceinline__ float exp2v(float x) {
  return __builtin_amdgcn_exp2f(x);
}
static __device__ __forceinline__ float log2v(float x) {
  return __builtin_amdgcn_logf(x);
}

// ---------------------------------------------------------------------------
// Normalize rows to unit L2 norm, split into bf16 hi/lo, and REPACK into the
// MFMA fragment-tile layout so the GEMM kernel's loads are lane-contiguous:
//   tile t (16 rows), chunk c in {0,1}, lane L = quad*16 + mrow:
//     offset(t,c,L,j) = t*1024 + c*512 + L*8 + j    (bf16 elements, j<8)
//     holds element [row = t*16 + mrow][k = c*32 + quad*8 + j].
// A-frag and B-frag (B^T GEMM) use the SAME layout -> one copy serves both.
// grid 256 x 256 thr; block = 32 rows (2 tiles) of x or y, via LDS transpose.
// ---------------------------------------------------------------------------
__global__ __launch_bounds__(256) void norm_repack_kernel(
    const float* __restrict__ x, const float* __restrict__ y,
    __bf16* __restrict__ xhf, __bf16* __restrict__ xlf,
    __bf16* __restrict__ yhf, __bf16* __restrict__ ylf) {
  __shared__ float tf[32][72];       // +8 pad: 16B-aligned rows, bank-spread
  int r0 = blockIdx.x * 32;
  const float* src;
  __bf16 *dh, *dl;
  int rbase;
  if (r0 < NPTS) { src = x; dh = xhf; dl = xlf; rbase = r0; }
  else           { src = y; dh = yhf; dl = ylf; rbase = r0 - NPTS; }

  int wave = threadIdx.x >> 6, lane = threadIdx.x & 63;
  #pragma unroll
  for (int i = 0; i < 8; ++i) {
    int wrow = wave * 8 + i;
    float v = src[(size_t)(rbase + wrow) * DIM + lane];
    float s = v * v;
    #pragma unroll
    for (int o = 32; o; o >>= 1) s += __shfl_xor(s, o, 64);
    tf[wrow][lane] = v * (1.0f / sqrtf(s));
  }
  __syncthreads();

  int tt   = threadIdx.x >> 7;        // tile within block (0/1)
  int idx  = threadIdx.x & 127;
  int c    = idx >> 6, L = idx & 63;
  int quad = L >> 4, mrow = L & 15;
  const float* rp = &tf[tt * 16 + mrow][c * 32 + quad * 8];
  bf16x8 hv, lv;
  #pragma unroll
  for (int j = 0; j < 8; ++j) {
    float v = rp[j];
    __bf16 h = (__bf16)v;
    hv[j] = h;
    lv[j] = (__bf16)(v - (float)h);
  }
  size_t ob = (size_t)(rbase / 16 + tt) * 1024 + c * 512 + L * 8;
  *(bf16x8*)(dh + ob) = hv;           // fully coalesced 16B/lane writes
  *(bf16x8*)(dl + ob) = lv;
}

// ---------------------------------------------------------------------------
// FUSED sweep (v4): recompute cost tiles via split-bf16 MFMA from the
// fragment-tile layout, feed fp32 accumulators straight into an online
// row-logsumexp in the base-2 log domain.
//
// Round-5 lesson: 32-row blocks re-read all of B per block -> 512 MB/sweep
// of L2 traffic (~15 us floor) and no prefetch left L2 latency partially
// exposed. Now: 64-row blocks (4 row-sets) halve B traffic to 256 MB and
// amortize each B-load over 48 MFMA; explicit double-buffer prefetch of the
// next tile-pair keeps 8 loads in flight across the compute phase
// (substitutes for the occupancy lost to the bigger register tile).
//
// Grid: 4 mats x 64 row-blocks = 256 blocks x 512 thr (8 waves) =
// 1 block/CU = 2 waves/SIMD. Block = 64 rows x 4096 cols; wave owns
// 512 cols = 32 col-tiles, processed in pairs (2-element blocked LSE:
// same (quad,q) slot of consecutive tiles is the same row).
// 6 MFMA per 16x16 tile (hi.hi c0,c1 + lo.hi c0,c1 + hi.lo c0,c1).
// C/D frag: col = L&15 (= h index), row = (L>>4)*4 + q within the row-set.
// tv = h2_j - cost*inv_eps2 = fma(min(dot,1), inv_eps2, h2_j - inv_eps2).
// Merge: shfl over 16 col-lanes, then LDS merge across 8 waves.
// Final: ft = -eps*ln(sum) = -(eps*ln2)*(m + log2(s)).
// ---------------------------------------------------------------------------
__global__ __launch_bounds__(512, 2) void fused_pass_kernel(
    const __bf16* __restrict__ xhf, const __bf16* __restrict__ xlf,
    const __bf16* __restrict__ yhf, const __bf16* __restrict__ ylf,
    const float* __restrict__ potOld, float* __restrict__ potNew,
    float inv_eps2, float epsl2, int use_pot, int avg) {
  __shared__ float hlds[NPTS];       // 16 KB: h2[j] = -12 + pot[j]*inv_eps2
  __shared__ float mred[8][64];
  __shared__ float sred[8][64];

  int mat = blockIdx.x >> 6;
  int rb  = blockIdx.x & 63;
  const __bf16 *Ah, *Al, *Bh, *Bl;
  if (mat == 0)      { Ah = xhf; Al = xlf; Bh = yhf; Bl = ylf; }
  else if (mat == 1) { Ah = yhf; Al = ylf; Bh = xhf; Bl = xlf; }
  else if (mat == 2) { Ah = xhf; Al = xlf; Bh = xhf; Bl = xlf; }
  else               { Ah = yhf; Al = ylf; Bh = yhf; Bl = ylf; }
  int ridx = (mat == 0) ? 1 : ((mat == 1) ? 0 : mat);
  const float* pot = potOld + (size_t)ridx * NPTS;

  // stage h2[] into LDS: 512 thr x 8 floats
  {
    int j8 = threadIdx.x * 8;
    float4 p0, p1;
    if (use_pot) {
      float4 q0 = *(const float4*)(pot + j8);
      float4 q1 = *(const float4*)(pot + j8 + 4);
      p0.x = fmaf(q0.x, inv_eps2, LOGW2); p0.y = fmaf(q0.y, inv_eps2, LOGW2);
      p0.z = fmaf(q0.z, inv_eps2, LOGW2); p0.w = fmaf(q0.w, inv_eps2, LOGW2);
      p1.x = fmaf(q1.x, inv_eps2, LOGW2); p1.y = fmaf(q1.y, inv_eps2, LOGW2);
      p1.z = fmaf(q1.z, inv_eps2, LOGW2); p1.w = fmaf(q1.w, inv_eps2, LOGW2);
    } else {
      p0.x = p0.y = p0.z = p0.w = LOGW2;
      p1 = p0;
    }
    *(float4*)(hlds + j8) = p0;
    *(float4*)(hlds + j8 + 4) = p1;
  }
  __syncthreads();

  int wave = threadIdx.x >> 6, L = threadIdx.x & 63;
  int mrow = L & 15, quad = L >> 4;
  int lofs = L * 8;
  int i0 = rb * 64;

  // A fragments: 4 row-sets (tiles rb*4 .. rb*4+3), 64 VGPR
  bf16x8 Ah0[4], Ah1[4], Al0[4], Al1[4];
  #pragma unroll
  for (int rs = 0; rs < 4; ++rs) {
    size_t ab = (size_t)(rb * 4 + rs) * 1024 + lofs;
    Ah0[rs] = *(const bf16x8*)(Ah + ab);
    Ah1[rs] = *(const bf16x8*)(Ah + ab + 512);
    Al0[rs] = *(const bf16x8*)(Al + ab);
    Al1[rs] = *(const bf16x8*)(Al + ab + 512);
  }

  // online-LSE state: 16 (m,s) pairs (4 sets x 4 sub-rows), base-2 log domain
  float sm[16], ss[16];
  #pragma unroll
  for (int i = 0; i < 16; ++i) { sm[i] = NEGINF; ss[i] = 0.0f; }

  size_t jt0 = (size_t)(wave * 32) * 1024 + lofs;   // wave's first tile
  int hb0 = wave * 512;

  // prefetch tile-pair 0
  bf16x8 c0h0 = *(const bf16x8*)(Bh + jt0);
  bf16x8 c0h1 = *(const bf16x8*)(Bh + jt0 + 512);
  bf16x8 c0l0 = *(const bf16x8*)(Bl + jt0);
  bf16x8 c0l1 = *(const bf16x8*)(Bl + jt0 + 512);
  bf16x8 c1h0 = *(const bf16x8*)(Bh + jt0 + 1024);
  bf16x8 c1h1 = *(const bf16x8*)(Bh + jt0 + 1536);
  bf16x8 c1l0 = *(const bf16x8*)(Bl + jt0 + 1024);
  bf16x8 c1l1 = *(const bf16x8*)(Bl + jt0 + 1536);

  #pragma unroll 1
  for (int tp = 0; tp < 16; ++tp) {
    // issue next pair's loads first (stay in flight across this pair's MFMA)
    int tpn = (tp < 15) ? tp + 1 : 15;
    size_t on = jt0 + (size_t)tpn * 2048;
    bf16x8 n0h0 = *(const bf16x8*)(Bh + on);
    bf16x8 n0h1 = *(const bf16x8*)(Bh + on + 512);
    bf16x8 n0l0 = *(const bf16x8*)(Bl + on);
    bf16x8 n0l1 = *(const bf16x8*)(Bl + on + 512);
    bf16x8 n1h0 = *(const bf16x8*)(Bh + on + 1024);
    bf16x8 n1h1 = *(const bf16x8*)(Bh + on + 1536);
    bf16x8 n1l0 = *(const bf16x8*)(Bl + on + 1024);
    bf16x8 n1l1 = *(const bf16x8*)(Bl + on + 1536);
    float hp0 = hlds[hb0 + tp * 32 + mrow] - inv_eps2;
    float hp1 = hlds[hb0 + tp * 32 + 16 + mrow] - inv_eps2;

    #pragma unroll
    for (int rs = 0; rs < 4; ++rs) {
      f32x4 acc0 = {0.0f, 0.0f, 0.0f, 0.0f};
      acc0 = mfma16(Ah0[rs], c0h0, acc0);
      acc0 = mfma16(Ah1[rs], c0h1, acc0);
      acc0 = mfma16(Al0[rs], c0h0, acc0);
      acc0 = mfma16(Al1[rs], c0h1, acc0);
      acc0 = mfma16(Ah0[rs], c0l0, acc0);
      acc0 = mfma16(Ah1[rs], c0l1, acc0);
      f32x4 acc1 = {0.0f, 0.0f, 0.0f, 0.0f};
      acc1 = mfma16(Ah0[rs], c1h0, acc1);
      acc1 = mfma16(Ah1[rs], c1h1, acc1);
      acc1 = mfma16(Al0[rs], c1h0, acc1);
      acc1 = mfma16(Al1[rs], c1h1, acc1);
      acc1 = mfma16(Ah0[rs], c1l0, acc1);
      acc1 = mfma16(Ah1[rs], c1l1, acc1);
      #pragma unroll
      for (int q = 0; q < 4; ++q) {
        int id = rs * 4 + q;
        float tv0 = fmaf(fminf(acc0[q], 1.0f), inv_eps2, hp0);
        float tv1 = fmaf(fminf(acc1[q], 1.0f), inv_eps2, hp1);
        float mn = fmaxf(sm[id], fmaxf(tv0, tv1));
        ss[id] = fmaf(ss[id], exp2v(sm[id] - mn),
                      exp2v(tv0 - mn) + exp2v(tv1 - mn));
        sm[id] = mn;
      }
    }
    c0h0 = n0h0; c0h1 = n0h1; c0l0 = n0l0; c0l1 = n0l1;
    c1h0 = n1h0; c1h1 = n1h1; c1l0 = n1l0; c1l1 = n1l1;
  }

  // merge (m,s) across the 16 col-lanes of each quad group
  #pragma unroll
  for (int o = 1; o < 16; o <<= 1) {
    #pragma unroll
    for (int i = 0; i < 16; ++i) {
      float m2 = __shfl_xor(sm[i], o, 64);
      float s2 = __shfl_xor(ss[i], o, 64);
      float mn = fmaxf(sm[i], m2);
      ss[i] = ss[i] * exp2v(sm[i] - mn) + s2 * exp2v(m2 - mn);
      sm[i] = mn;
    }
  }

  // per-wave partials -> LDS (row within block = rs*16 + quad*4 + q)
  if (mrow == 0) {
    #pragma unroll
    for (int rs = 0; rs < 4; ++rs)
      #pragma unroll
      for (int q = 0; q < 4; ++q) {
        int row = rs * 16 + quad * 4 + q;
        mred[wave][row] = sm[rs * 4 + q];
        sred[wave][row] = ss[rs * 4 + q];
      }
  }
  __syncthreads();

  // merge 8 waves (disjoint col ranges), finalize, write potential
  if (threadIdx.x < 64) {
    int row = threadIdx.x;
    float m = mred[0][row], s = sred[0][row];
    #pragma unroll
    for (int w = 1; w < 8; ++w) {
      float m2 = mred[w][row], s2 = sred[w][row];
      float mn = fmaxf(m, m2);
      s = s * exp2v(m - mn) + s2 * exp2v(m2 - mn);
      m = mn;
    }
    float ft = -epsl2 * (m + log2v(s));
    float v = avg ? 0.5f * (potOld[(size_t)mat * NPTS + i0 + row] + ft) : ft;
    potNew[(size_t)mat * NPTS + i0 + row] = v;
  }
}

// ---------------------------------------------------------------------------
// out = mean(f_ba - f_aa) + mean(g_ab - g_bb), potentials at pot[0..3][NPTS]
// ---------------------------------------------------------------------------
__global__ __launch_bounds__(256) void final_kernel(
    const float* __restrict__ pot, float* __restrict__ out) {
  __shared__ float red[256];
  float s = 0.0f;
  for (int j = threadIdx.x; j < NPTS; j += 256)
    s += (pot[j] - pot[2 * NPTS + j]) + (pot[NPTS + j] - pot[3 * NPTS + j]);
  red[threadIdx.x] = s;
  __syncthreads();
  #pragma unroll
  for (int o = 128; o; o >>= 1) {
    if (threadIdx.x < o) red[threadIdx.x] += red[threadIdx.x + o];
    __syncthreads();
  }
  if (threadIdx.x == 0) out[0] = red[0] / (float)NPTS;
}

extern "C" void kernel_launch(void* const* d_in, const int* in_sizes, int n_in,
                              void* d_out, int out_size, void* d_ws, size_t ws_size,
                              hipStream_t stream) {
  const float* x = (const float*)d_in[0];
  const float* y = (const float*)d_in[1];
  char* ws = (char*)d_ws;

  // workspace layout (~2.2 MB): fragment-packed hi/lo matrices + potentials
  __bf16* xhf = (__bf16*)ws;
  __bf16* xlf = xhf + (size_t)NPTS * DIM;
  __bf16* yhf = xlf + (size_t)NPTS * DIM;
  __bf16* ylf = yhf + (size_t)NPTS * DIM;
  float* potA = (float*)(ylf + (size_t)NPTS * DIM);   // 4 * NPTS
  float* potB = potA + 4 * (size_t)NPTS;
  size_t needed = (size_t)((char*)(potB + 4 * (size_t)NPTS) - ws);
  if (ws_size < needed) return;

  norm_repack_kernel<<<256, 256, 0, stream>>>(x, y, xhf, xlf, yhf, ylf);

  // geomloss epsilon schedule (p=2, blur=0.05, scaling=0.8, diameter=2)
  double lst[32];
  int c = 0;
  lst[c++] = 4.0;
  double start = 2.0 * log(2.0), stop = 2.0 * log(0.05), step = 2.0 * log(0.8);
  for (int k = 0;; ++k) {
    double v = start + (double)k * step;
    if (v <= stop) break;
    lst[c++] = exp(v);
  }
  lst[c++] = 0.05 * 0.05;   // c == 19

  const double LOG2E = 1.4426950408889634074;
  const double LN2   = 0.6931471805599453094;

  // sweeps: p=0 init (no pot, assign); p=1..c loop (avg); p=c+1 final (assign)
  for (int p = 0; p < c + 2; ++p) {
    double e = (p == 0) ? lst[0] : ((p <= c) ? lst[p - 1] : lst[c - 1]);
    float inv_eps2 = (float)(LOG2E / e);   // log2(e)/eps
    float epsl2    = (float)(e * LN2);     // eps*ln(2)
    int use_pot = (p > 0) ? 1 : 0;
    int avg = (p >= 1 && p <= c) ? 1 : 0;
    const float* po = (p & 1) ? potB : potA;
    float* pn       = (p & 1) ? potA : potB;
    fused_pass_kernel<<<256, 512, 0, stream>>>(xhf, xlf, yhf, ylf, po, pn,
                                               inv_eps2, epsl2, use_pot, avg);
  }
  // c+2 = 21 sweeps; last sweep (p=20, even) wrote potB
  final_kernel<<<1, 256, 0, stream>>>(potB, (float*)d_out);
}